// Round 2
// baseline (852.898 us; speedup 1.0000x reference)
//
#include <hip/hip_runtime.h>
#include <cstdint>
#include <cstddef>

typedef unsigned short u16;
typedef __bf16 bf16x8 __attribute__((ext_vector_type(8)));
typedef float f32x4 __attribute__((ext_vector_type(4)));

// Problem constants
#define BB 2
#define SS 4096
#define DD 2048
#define HH 16
#define HD 128
#define CC 64
#define NC 64
#define D5 10240
#define RMS_EPS 1.1920928955078125e-07f

__device__ __forceinline__ u16 f2bf(float f) {
  uint32_t x = __float_as_uint(f);
  uint32_t r = (x + 0x7fffu + ((x >> 16) & 1u)) >> 16;
  return (u16)r;
}
__device__ __forceinline__ float bf2f(u16 u) {
  return __uint_as_float(((uint32_t)u) << 16);
}
__device__ __forceinline__ float sigmoidf_(float x) {
  return 1.0f / (1.0f + expf(-x));
}

// ---------------------------------------------------------------------------
// fp32 -> bf16 convert (grid-stride)
// ---------------------------------------------------------------------------
__global__ void cvt_bf16_kernel(const float* __restrict__ src, u16* __restrict__ dst, int n) {
  int i = blockIdx.x * blockDim.x + threadIdx.x;
  int stride = gridDim.x * blockDim.x;
  for (; i < n; i += stride) dst[i] = f2bf(src[i]);
}

// ---------------------------------------------------------------------------
// bf16 GEMM, C[M,N] = A[M,K] * B[N,K]^T. OutT = float or u16 (bf16).
// m97-style: 128x128 tile, BK=32, 4 waves, each wave 64x64 via 4x4 MFMA tiles,
// global_load_lds width-16 staging, 2-barrier K loop.
// ---------------------------------------------------------------------------
template <typename OutT>
__global__ __launch_bounds__(256) void gemm_bt(const u16* __restrict__ A,
                                               const u16* __restrict__ B,
                                               OutT* __restrict__ C,
                                               int M, int N, int K) {
  __shared__ u16 As[128 * 32];  // [m][k] row-major, 8 KiB
  __shared__ u16 Bs[128 * 32];  // [n][k] row-major, 8 KiB

  const int tid = threadIdx.x;
  const int wave = tid >> 6;
  const int lane = tid & 63;
  const int m0 = blockIdx.x * 128;
  const int n0 = blockIdx.y * 128;
  const int wm = (wave & 1) * 64;   // wave quadrant
  const int wn = (wave >> 1) * 64;

  f32x4 acc[4][4] = {};

  // Staging: each wave covers 32 rows (2 instructions x 16 rows). Lane l of an
  // instruction handles row (l>>2), 16B chunk (l&3). LDS dest = wave-uniform
  // base + lane*16B, matching row-major [row][k] contiguity exactly.
  const int srow = wave * 32 + (lane >> 2);
  const int scol = (lane & 3) * 8;
  const u16* Ag0 = A + (size_t)(m0 + srow) * K + scol;
  const u16* Ag1 = A + (size_t)(m0 + srow + 16) * K + scol;
  const u16* Bg0 = B + (size_t)(n0 + srow) * K + scol;
  const u16* Bg1 = B + (size_t)(n0 + srow + 16) * K + scol;
  u16* Al0 = &As[(wave * 32) * 32];
  u16* Al1 = &As[(wave * 32 + 16) * 32];
  u16* Bl0 = &Bs[(wave * 32) * 32];
  u16* Bl1 = &Bs[(wave * 32 + 16) * 32];

  // MFMA fragment coords: A[m = lane&15][k = (lane>>4)*8 + j], same for B.
  const int fr = lane & 15;
  const int fk = (lane >> 4) * 8;

  for (int k0 = 0; k0 < K; k0 += 32) {
    __builtin_amdgcn_global_load_lds(
        (__attribute__((address_space(1))) void*)(u16*)(Ag0 + k0),
        (__attribute__((address_space(3))) void*)Al0, 16, 0, 0);
    __builtin_amdgcn_global_load_lds(
        (__attribute__((address_space(1))) void*)(u16*)(Ag1 + k0),
        (__attribute__((address_space(3))) void*)Al1, 16, 0, 0);
    __builtin_amdgcn_global_load_lds(
        (__attribute__((address_space(1))) void*)(u16*)(Bg0 + k0),
        (__attribute__((address_space(3))) void*)Bl0, 16, 0, 0);
    __builtin_amdgcn_global_load_lds(
        (__attribute__((address_space(1))) void*)(u16*)(Bg1 + k0),
        (__attribute__((address_space(3))) void*)Bl1, 16, 0, 0);
    __syncthreads();

    bf16x8 af[4], bfg[4];
#pragma unroll
    for (int i = 0; i < 4; ++i)
      af[i] = *(const bf16x8*)&As[(wm + i * 16 + fr) * 32 + fk];
#pragma unroll
    for (int j = 0; j < 4; ++j)
      bfg[j] = *(const bf16x8*)&Bs[(wn + j * 16 + fr) * 32 + fk];

#pragma unroll
    for (int i = 0; i < 4; ++i)
#pragma unroll
      for (int j = 0; j < 4; ++j)
        acc[i][j] = __builtin_amdgcn_mfma_f32_16x16x32_bf16(af[i], bfg[j], acc[i][j], 0, 0, 0);

    __syncthreads();
  }

  // Epilogue: C/D layout col = lane&15, row = (lane>>4)*4 + reg (m89-verified).
  const int crow = (lane >> 4) * 4;
  const int ccol = lane & 15;
#pragma unroll
  for (int i = 0; i < 4; ++i) {
#pragma unroll
    for (int j = 0; j < 4; ++j) {
      size_t r = (size_t)(m0 + wm + i * 16 + crow);
      size_t c = (size_t)(n0 + wn + j * 16 + ccol);
      OutT* Cp = C + r * N + c;
#pragma unroll
      for (int rr = 0; rr < 4; ++rr) {
        if constexpr (sizeof(OutT) == 2)
          Cp[(size_t)rr * N] = (OutT)f2bf(acc[i][j][rr]);
        else
          Cp[(size_t)rr * N] = acc[i][j][rr];
      }
    }
  }
}

// ---------------------------------------------------------------------------
// Scan phase A: per-chunk local pass (state_in = 0), fp32 replication of
//   prefix = cumprod(a); acc = cumsum(u / max(prefix,1e-6))
// One block (128 threads = hd) per (b, chunk, h). Emits ONLY the chunk
// carries P = prefix[63], L = prefix[63]*acc[63].
// ---------------------------------------------------------------------------
__global__ __launch_bounds__(128) void scan_chunk(const u16* __restrict__ proj,
                                                  float* __restrict__ Pc,
                                                  float* __restrict__ Lc) {
  const int idx = blockIdx.x;            // ((b*NC + c)*HH + h)
  const int h = idx & (HH - 1);
  const int c = (idx >> 4) & (NC - 1);
  const int b = idx >> 10;
  const int d = threadIdx.x;

  const size_t row0 = (size_t)(b * SS + c * CC) * D5 + h * HD + d;

  float pref = 1.0f, acc = 0.0f;
  for (int t = 0; t < CC; ++t) {
    const size_t rp = row0 + (size_t)t * D5;
    float kraw = bf2f(proj[rp + DD]);
    float vval = bf2f(proj[rp + 2 * DD]);
    float araw = bf2f(proj[rp + 3 * DD]);
    float a = sigmoidf_(araw + 2.0f);
    a = fminf(fmaxf(a, 0.6f), 0.9995f);
    pref *= a;
    acc += tanhf(kraw) * vval / fmaxf(pref, 1e-6f);
  }
  const size_t ci = ((size_t)(b * NC + c) * HH + h) * HD + d;  // [b][c][h*hd]
  Pc[ci] = pref;
  Lc[ci] = pref * acc;
}

// ---------------------------------------------------------------------------
// Scan phase B: inter-chunk carry. 4096 threads, one per (b, h*hd) channel.
// Sin[c] = incoming state for chunk c; state_c = P_c*state_{c-1} + L_c.
// ---------------------------------------------------------------------------
__global__ void scan_carry(const float* __restrict__ Pc, const float* __restrict__ Lc,
                           float* __restrict__ Sin) {
  const int t = blockIdx.x * blockDim.x + threadIdx.x;  // < BB*DD
  const int b = t >> 11;
  const int hd = t & (DD - 1);
  float state = 0.0f;
  for (int c = 0; c < NC; ++c) {
    const size_t i = (size_t)(b * NC + c) * DD + hd;
    Sin[i] = state;
    state = Pc[i] * state + Lc[i];
  }
}

// ---------------------------------------------------------------------------
// Scan phase C / finalize: recompute chunk-local recurrence, combine with
// carried state:  mem_t = prefix_t * (state_in + acc_t)   (ref association),
// q RMS-norm over hd, y = gate*(qn*mem) + (1-gate)*v  -> bf16 for GEMM2.
// One block (128 threads = hd) per (b, chunk, h); t loop inside.
// ---------------------------------------------------------------------------
__global__ __launch_bounds__(128) void finalize_y(const u16* __restrict__ proj,
                                                  const float* __restrict__ Sin,
                                                  u16* __restrict__ y) {
  const int idx = blockIdx.x;            // ((b*NC + c)*HH + h)
  const int h = idx & (HH - 1);
  const int c = (idx >> 4) & (NC - 1);
  const int b = idx >> 10;
  const int d = threadIdx.x;

  __shared__ float sh[2];

  const size_t row0 = (size_t)(b * SS + c * CC) * D5 + h * HD + d;
  const size_t out0 = (size_t)(b * SS + c * CC) * DD + h * HD + d;
  const float sin_v = Sin[(size_t)(b * NC + c) * DD + h * HD + d];

  float pref = 1.0f, acc = 0.0f;
  for (int t = 0; t < CC; ++t) {
    const size_t rp = row0 + (size_t)t * D5;
    const float q = bf2f(proj[rp]);
    const float kraw = bf2f(proj[rp + DD]);
    const float vval = bf2f(proj[rp + 2 * DD]);
    const float araw = bf2f(proj[rp + 3 * DD]);
    const float graw = bf2f(proj[rp + 4 * DD]);

    float a = sigmoidf_(araw + 2.0f);
    a = fminf(fmaxf(a, 0.6f), 0.9995f);
    pref *= a;
    acc += tanhf(kraw) * vval / fmaxf(pref, 1e-6f);
    const float mem = pref * (sin_v + acc);

    // RMS-norm of q over hd (128 lanes = the whole block)
    float ss2 = q * q;
#pragma unroll
    for (int m = 32; m; m >>= 1) ss2 += __shfl_xor(ss2, m);
    __syncthreads();                       // protect sh vs previous iteration
    if ((d & 63) == 0) sh[d >> 6] = ss2;
    __syncthreads();
    const float tot = sh[0] + sh[1];
    const float qn = q * rsqrtf(tot * (1.0f / 128.0f) + RMS_EPS);

    const float gate = sigmoidf_(graw);
    y[out0 + (size_t)t * DD] = f2bf(gate * (qn * mem) + (1.0f - gate) * vval);
  }
}

// ---------------------------------------------------------------------------
extern "C" void kernel_launch(void* const* d_in, const int* in_sizes, int n_in,
                              void* d_out, int out_size, void* d_ws, size_t ws_size,
                              hipStream_t stream) {
  const float* x = (const float*)d_in[0];      // [2,4096,2048]
  const float* w_in = (const float*)d_in[1];   // [10240,2048]
  const float* w_out = (const float*)d_in[2];  // [2048,2048]
  float* out = (float*)d_out;                  // [2,4096,2048] fp32

  char* ws = (char*)d_ws;
  size_t off = 0;
  auto alloc = [&](size_t bytes) -> void* {
    void* p = ws + off;
    off += (bytes + 255) & ~(size_t)255;
    return p;
  };
  const size_t nBS = (size_t)BB * SS;              // 8192
  u16* projb = (u16*)alloc(nBS * D5 * 2);          // 167.8 MB (bf16 proj)
  u16* xb    = (u16*)alloc(nBS * DD * 2);          // 33.6 MB (reused as yb)
  u16* wib   = (u16*)alloc((size_t)D5 * DD * 2);   // 41.9 MB
  u16* wob   = (u16*)alloc((size_t)DD * DD * 2);   // 8.4 MB
  float* Pc  = (float*)alloc((size_t)BB * NC * DD * 4);  // 1 MB
  float* Lc  = (float*)alloc((size_t)BB * NC * DD * 4);  // 1 MB
  float* Sin = (float*)alloc((size_t)BB * NC * DD * 4);  // 1 MB
  u16* yb = xb;  // xb dead after GEMM1; reuse for y
  (void)in_sizes; (void)n_in; (void)out_size;

  // Workspace guard: if d_ws is too small, skip all launches -> clean absmax
  // failure (output stays zero) instead of a GPU memory fault / core dump.
  if (off > ws_size) return;

  // 1) bf16 casts of x, w_in, w_out
  cvt_bf16_kernel<<<2048, 256, 0, stream>>>(x, xb, (int)(nBS * DD));
  cvt_bf16_kernel<<<2048, 256, 0, stream>>>(w_in, wib, (int)((size_t)D5 * DD));
  cvt_bf16_kernel<<<2048, 256, 0, stream>>>(w_out, wob, (int)((size_t)DD * DD));

  // 2) proj = x @ w_in^T   [8192 x 10240], K=2048, bf16 out
  gemm_bt<u16><<<dim3(64, 80), 256, 0, stream>>>(xb, wib, projb, 8192, 10240, 2048);

  // 3) chunk-local scan -> per-chunk carries only
  scan_chunk<<<BB * NC * HH, 128, 0, stream>>>(projb, Pc, Lc);

  // 4) inter-chunk carry scan
  scan_carry<<<16, 256, 0, stream>>>(Pc, Lc, Sin);

  // 5) finalize y (recompute local scan, rmsnorm q, gates) -> bf16 (into xb)
  finalize_y<<<BB * NC * HH, 128, 0, stream>>>(projb, Sin, yb);

  // 6) out = y @ w_out^T   [8192 x 2048], K=2048, fp32 out
  gemm_bt<float><<<dim3(64, 16), 256, 0, stream>>>(yb, wob, out, 8192, 2048, 2048);
}

// Round 3
// 830.515 us; speedup vs baseline: 1.0270x; 1.0270x over previous
//
#include <hip/hip_runtime.h>
#include <cstdint>
#include <cstddef>

typedef unsigned short u16;
typedef __bf16 bf16x8 __attribute__((ext_vector_type(8)));
typedef float f32x4 __attribute__((ext_vector_type(4)));

// Problem constants
#define BB 2
#define SS 4096
#define DD 2048
#define HH 16
#define HD 128
#define CC 64
#define NC 64
#define D5 10240
#define RMS_EPS 1.1920928955078125e-07f

__device__ __forceinline__ u16 f2bf(float f) {
  uint32_t x = __float_as_uint(f);
  uint32_t r = (x + 0x7fffu + ((x >> 16) & 1u)) >> 16;
  return (u16)r;
}
__device__ __forceinline__ float bf2f(u16 u) {
  return __uint_as_float(((uint32_t)u) << 16);
}
__device__ __forceinline__ float fast_sigmoid(float x) {
  return 1.0f / (1.0f + __expf(-x));
}
__device__ __forceinline__ float fast_tanh(float x) {
  // tanh(x) = 1 - 2/(exp(2x)+1); ~1e-7 rel err with __expf, fine vs 7.75e-2 budget
  return 1.0f - 2.0f / (__expf(2.0f * x) + 1.0f);
}

// ---------------------------------------------------------------------------
// fp32 -> bf16 convert (grid-stride)
// ---------------------------------------------------------------------------
__global__ void cvt_bf16_kernel(const float* __restrict__ src, u16* __restrict__ dst, int n) {
  int i = blockIdx.x * blockDim.x + threadIdx.x;
  int stride = gridDim.x * blockDim.x;
  for (; i < n; i += stride) dst[i] = f2bf(src[i]);
}

// ---------------------------------------------------------------------------
// bf16 GEMM, C[M,N] = A[M,K] * B[N,K]^T. OutT = float or u16 (bf16).
// 128x128 tile, BK=32, 4 waves x (64x64 via 4x4 MFMA 16x16x32),
// global_load_lds width-16 staging.
//
// LDS bank-conflict fix (R3): XOR-swizzled chunk placement. Row r's logical
// 16B chunk c lives at physical chunk c ^ ((r>>1)&3). The global_load_lds LDS
// dest is fixed (wave-uniform base + lane*16 — m104), so the swizzle is
// applied by permuting the per-lane global SOURCE chunk. Fragment reads then
// hit all 8 four-bank slots per 16-lane phase (2-way aliasing = free, m136)
// instead of 2 slots (8-way conflict, 2.94x).
// ---------------------------------------------------------------------------
template <typename OutT>
__global__ __launch_bounds__(256) void gemm_bt(const u16* __restrict__ A,
                                               const u16* __restrict__ B,
                                               OutT* __restrict__ C,
                                               int M, int N, int K) {
  __shared__ u16 As[128 * 32];  // [m][k] row-major 64B rows, swizzled chunks
  __shared__ u16 Bs[128 * 32];

  const int tid = threadIdx.x;
  const int wave = tid >> 6;
  const int lane = tid & 63;
  const int m0 = blockIdx.x * 128;
  const int n0 = blockIdx.y * 128;
  const int wm = (wave & 1) * 64;   // wave quadrant
  const int wn = (wave >> 1) * 64;

  f32x4 acc[4][4] = {};

  // Staging: wave covers 32 rows (2 insts x 16 rows). Lane l: row_local=l>>2,
  // physical chunk l&3 -> fetch logical chunk (l&3) ^ ((l>>3)&3)
  // (= pc ^ ((row>>1)&3); row bits 1-2 == (l>>2) bits 1-2, invariant under
  //  wave*32 and +16 offsets).
  const int srow = wave * 32 + (lane >> 2);
  const int scol = ((lane & 3) ^ ((lane >> 3) & 3)) * 8;  // swizzled source chunk
  const u16* Ag0 = A + (size_t)(m0 + srow) * K + scol;
  const u16* Ag1 = A + (size_t)(m0 + srow + 16) * K + scol;
  const u16* Bg0 = B + (size_t)(n0 + srow) * K + scol;
  const u16* Bg1 = B + (size_t)(n0 + srow + 16) * K + scol;
  u16* Al0 = &As[(wave * 32) * 32];
  u16* Al1 = &As[(wave * 32 + 16) * 32];
  u16* Bl0 = &Bs[(wave * 32) * 32];
  u16* Bl1 = &Bs[(wave * 32 + 16) * 32];

  // Fragment coords: A[m = lane&15][k = (lane>>4)*8 + j]. Logical chunk
  // c = lane>>4; physical chunk = c ^ ((fr>>1)&3) = c ^ ((lane>>1)&3).
  const int fr = lane & 15;
  const int fk = ((lane >> 4) ^ ((lane >> 1) & 3)) * 8;

  for (int k0 = 0; k0 < K; k0 += 32) {
    __builtin_amdgcn_global_load_lds(
        (__attribute__((address_space(1))) void*)(u16*)(Ag0 + k0),
        (__attribute__((address_space(3))) void*)Al0, 16, 0, 0);
    __builtin_amdgcn_global_load_lds(
        (__attribute__((address_space(1))) void*)(u16*)(Ag1 + k0),
        (__attribute__((address_space(3))) void*)Al1, 16, 0, 0);
    __builtin_amdgcn_global_load_lds(
        (__attribute__((address_space(1))) void*)(u16*)(Bg0 + k0),
        (__attribute__((address_space(3))) void*)Bl0, 16, 0, 0);
    __builtin_amdgcn_global_load_lds(
        (__attribute__((address_space(1))) void*)(u16*)(Bg1 + k0),
        (__attribute__((address_space(3))) void*)Bl1, 16, 0, 0);
    __syncthreads();

    bf16x8 af[4], bfg[4];
#pragma unroll
    for (int i = 0; i < 4; ++i)
      af[i] = *(const bf16x8*)&As[(wm + i * 16 + fr) * 32 + fk];
#pragma unroll
    for (int j = 0; j < 4; ++j)
      bfg[j] = *(const bf16x8*)&Bs[(wn + j * 16 + fr) * 32 + fk];

#pragma unroll
    for (int i = 0; i < 4; ++i)
#pragma unroll
      for (int j = 0; j < 4; ++j)
        acc[i][j] = __builtin_amdgcn_mfma_f32_16x16x32_bf16(af[i], bfg[j], acc[i][j], 0, 0, 0);

    __syncthreads();
  }

  // Epilogue: C/D layout col = lane&15, row = (lane>>4)*4 + reg (m89-verified).
  const int crow = (lane >> 4) * 4;
  const int ccol = lane & 15;
#pragma unroll
  for (int i = 0; i < 4; ++i) {
#pragma unroll
    for (int j = 0; j < 4; ++j) {
      size_t r = (size_t)(m0 + wm + i * 16 + crow);
      size_t c = (size_t)(n0 + wn + j * 16 + ccol);
      OutT* Cp = C + r * N + c;
#pragma unroll
      for (int rr = 0; rr < 4; ++rr) {
        if constexpr (sizeof(OutT) == 2)
          Cp[(size_t)rr * N] = (OutT)f2bf(acc[i][j][rr]);
        else
          Cp[(size_t)rr * N] = acc[i][j][rr];
      }
    }
  }
}

// ---------------------------------------------------------------------------
// Scan phase A: per-chunk local pass (state_in = 0), fp32 replication of
//   prefix = cumprod(a); acc = cumsum(u / max(prefix,1e-6))
// One wave (64 threads) per (b, chunk, h); each lane owns d=lane and d=lane+64.
// Emits only chunk carries P = prefix[63], L = prefix[63]*acc[63].
// ---------------------------------------------------------------------------
__global__ __launch_bounds__(64) void scan_chunk(const u16* __restrict__ proj,
                                                 float* __restrict__ Pc,
                                                 float* __restrict__ Lc) {
  const int idx = blockIdx.x;            // ((b*NC + c)*HH + h)
  const int h = idx & (HH - 1);
  const int c = (idx >> 4) & (NC - 1);
  const int b = idx >> 10;
  const int lane = threadIdx.x;

  const size_t row0 = (size_t)(b * SS + c * CC) * D5 + h * HD;

  float p0 = 1.0f, a0 = 0.0f, p1 = 1.0f, a1 = 0.0f;
  for (int t = 0; t < CC; ++t) {
    const size_t rp = row0 + (size_t)t * D5;
    float k0 = bf2f(proj[rp + DD + lane]);
    float k1 = bf2f(proj[rp + DD + lane + 64]);
    float v0 = bf2f(proj[rp + 2 * DD + lane]);
    float v1 = bf2f(proj[rp + 2 * DD + lane + 64]);
    float ar0 = bf2f(proj[rp + 3 * DD + lane]);
    float ar1 = bf2f(proj[rp + 3 * DD + lane + 64]);
    float aa0 = fminf(fmaxf(fast_sigmoid(ar0 + 2.0f), 0.6f), 0.9995f);
    float aa1 = fminf(fmaxf(fast_sigmoid(ar1 + 2.0f), 0.6f), 0.9995f);
    p0 *= aa0;
    p1 *= aa1;
    a0 += fast_tanh(k0) * v0 / fmaxf(p0, 1e-6f);
    a1 += fast_tanh(k1) * v1 / fmaxf(p1, 1e-6f);
  }
  const size_t ci = ((size_t)(b * NC + c) * HH + h) * HD;  // [b][c][h*hd]
  Pc[ci + lane] = p0;
  Pc[ci + lane + 64] = p1;
  Lc[ci + lane] = p0 * a0;
  Lc[ci + lane + 64] = p1 * a1;
}

// ---------------------------------------------------------------------------
// Scan phase B: inter-chunk carry. 4096 threads, one per (b, h*hd) channel.
// Sin[c] = incoming state for chunk c; state_c = P_c*state_{c-1} + L_c.
// ---------------------------------------------------------------------------
__global__ void scan_carry(const float* __restrict__ Pc, const float* __restrict__ Lc,
                           float* __restrict__ Sin) {
  const int t = blockIdx.x * blockDim.x + threadIdx.x;  // < BB*DD
  const int b = t >> 11;
  const int hd = t & (DD - 1);
  float state = 0.0f;
  for (int c = 0; c < NC; ++c) {
    const size_t i = (size_t)(b * NC + c) * DD + hd;
    Sin[i] = state;
    state = Pc[i] * state + Lc[i];
  }
}

// ---------------------------------------------------------------------------
// Scan phase C / finalize: recompute chunk-local recurrence, combine with
// carried state: mem_t = prefix_t * (state_in + acc_t) (ref association),
// q RMS-norm over hd, y = gate*(qn*mem) + (1-gate)*v -> bf16 for GEMM2.
// One wave per (b, chunk, h); lane owns d=lane and d=lane+64 so the RMS
// reduction is a pure wave shfl_xor — no LDS, no __syncthreads.
// ---------------------------------------------------------------------------
__global__ __launch_bounds__(64) void finalize_y(const u16* __restrict__ proj,
                                                 const float* __restrict__ Sin,
                                                 u16* __restrict__ y) {
  const int idx = blockIdx.x;            // ((b*NC + c)*HH + h)
  const int h = idx & (HH - 1);
  const int c = (idx >> 4) & (NC - 1);
  const int b = idx >> 10;
  const int lane = threadIdx.x;

  const size_t row0 = (size_t)(b * SS + c * CC) * D5 + h * HD;
  const size_t out0 = (size_t)(b * SS + c * CC) * DD + h * HD;
  const size_t sinb = (size_t)(b * NC + c) * DD + h * HD;
  const float sin0 = Sin[sinb + lane];
  const float sin1 = Sin[sinb + lane + 64];

  float p0 = 1.0f, a0 = 0.0f, p1 = 1.0f, a1 = 0.0f;
  for (int t = 0; t < CC; ++t) {
    const size_t rp = row0 + (size_t)t * D5;
    const float q0 = bf2f(proj[rp + lane]);
    const float q1 = bf2f(proj[rp + lane + 64]);
    const float k0 = bf2f(proj[rp + DD + lane]);
    const float k1 = bf2f(proj[rp + DD + lane + 64]);
    const float v0 = bf2f(proj[rp + 2 * DD + lane]);
    const float v1 = bf2f(proj[rp + 2 * DD + lane + 64]);
    const float ar0 = bf2f(proj[rp + 3 * DD + lane]);
    const float ar1 = bf2f(proj[rp + 3 * DD + lane + 64]);
    const float g0 = bf2f(proj[rp + 4 * DD + lane]);
    const float g1 = bf2f(proj[rp + 4 * DD + lane + 64]);

    const float aa0 = fminf(fmaxf(fast_sigmoid(ar0 + 2.0f), 0.6f), 0.9995f);
    const float aa1 = fminf(fmaxf(fast_sigmoid(ar1 + 2.0f), 0.6f), 0.9995f);
    p0 *= aa0;
    p1 *= aa1;
    a0 += fast_tanh(k0) * v0 / fmaxf(p0, 1e-6f);
    a1 += fast_tanh(k1) * v1 / fmaxf(p1, 1e-6f);
    const float mem0 = p0 * (sin0 + a0);
    const float mem1 = p1 * (sin1 + a1);

    // RMS-norm of q over hd=128: both halves, wave-wide shfl reduction
    float ss = q0 * q0 + q1 * q1;
#pragma unroll
    for (int m = 32; m; m >>= 1) ss += __shfl_xor(ss, m);
    const float rn = rsqrtf(ss * (1.0f / 128.0f) + RMS_EPS);

    const float gt0 = fast_sigmoid(g0);
    const float gt1 = fast_sigmoid(g1);
    y[out0 + (size_t)t * DD + lane] = f2bf(gt0 * (q0 * rn * mem0) + (1.0f - gt0) * v0);
    y[out0 + (size_t)t * DD + lane + 64] = f2bf(gt1 * (q1 * rn * mem1) + (1.0f - gt1) * v1);
  }
}

// ---------------------------------------------------------------------------
extern "C" void kernel_launch(void* const* d_in, const int* in_sizes, int n_in,
                              void* d_out, int out_size, void* d_ws, size_t ws_size,
                              hipStream_t stream) {
  const float* x = (const float*)d_in[0];      // [2,4096,2048]
  const float* w_in = (const float*)d_in[1];   // [10240,2048]
  const float* w_out = (const float*)d_in[2];  // [2048,2048]
  float* out = (float*)d_out;                  // [2,4096,2048] fp32

  char* ws = (char*)d_ws;
  size_t off = 0;
  auto alloc = [&](size_t bytes) -> void* {
    void* p = ws + off;
    off += (bytes + 255) & ~(size_t)255;
    return p;
  };
  const size_t nBS = (size_t)BB * SS;              // 8192
  u16* projb = (u16*)alloc(nBS * D5 * 2);          // 167.8 MB (bf16 proj)
  u16* xb    = (u16*)alloc(nBS * DD * 2);          // 33.6 MB (reused as yb)
  u16* wib   = (u16*)alloc((size_t)D5 * DD * 2);   // 41.9 MB
  u16* wob   = (u16*)alloc((size_t)DD * DD * 2);   // 8.4 MB
  float* Pc  = (float*)alloc((size_t)BB * NC * DD * 4);  // 1 MB
  float* Lc  = (float*)alloc((size_t)BB * NC * DD * 4);  // 1 MB
  float* Sin = (float*)alloc((size_t)BB * NC * DD * 4);  // 1 MB
  u16* yb = xb;  // xb dead after GEMM1; reuse for y
  (void)in_sizes; (void)n_in; (void)out_size;

  // Workspace guard: clean zero-output failure instead of memory fault.
  if (off > ws_size) return;

  // 1) bf16 casts of x, w_in, w_out
  cvt_bf16_kernel<<<2048, 256, 0, stream>>>(x, xb, (int)(nBS * DD));
  cvt_bf16_kernel<<<2048, 256, 0, stream>>>(w_in, wib, (int)((size_t)D5 * DD));
  cvt_bf16_kernel<<<2048, 256, 0, stream>>>(w_out, wob, (int)((size_t)DD * DD));

  // 2) proj = x @ w_in^T   [8192 x 10240], K=2048, bf16 out
  gemm_bt<u16><<<dim3(64, 80), 256, 0, stream>>>(xb, wib, projb, 8192, 10240, 2048);

  // 3) chunk-local scan -> per-chunk carries only
  scan_chunk<<<BB * NC * HH, 64, 0, stream>>>(projb, Pc, Lc);

  // 4) inter-chunk carry scan
  scan_carry<<<16, 256, 0, stream>>>(Pc, Lc, Sin);

  // 5) finalize y (recompute local scan, rmsnorm q, gates) -> bf16 (into xb)
  finalize_y<<<BB * NC * HH, 64, 0, stream>>>(projb, Sin, yb);

  // 6) out = y @ w_out^T   [8192 x 2048], K=2048, fp32 out
  gemm_bt<float><<<dim3(64, 16), 256, 0, stream>>>(yb, wob, out, 8192, 2048, 2048);
}

// Round 4
// 801.350 us; speedup vs baseline: 1.0643x; 1.0364x over previous
//
#include <hip/hip_runtime.h>
#include <cstdint>
#include <cstddef>

typedef unsigned short u16;
typedef __bf16 bf16x8 __attribute__((ext_vector_type(8)));
typedef float f32x16 __attribute__((ext_vector_type(16)));
typedef unsigned int u32;
typedef u32 u32x4 __attribute__((ext_vector_type(4)));
typedef float f32x4v __attribute__((ext_vector_type(4)));

// Problem constants
#define BB 2
#define SS 4096
#define DD 2048
#define HH 16
#define HD 128
#define CC 64
#define NC 64
#define D5 10240
#define RMS_EPS 1.1920928955078125e-07f

__device__ __forceinline__ u16 f2bf(float f) {
  uint32_t x = __float_as_uint(f);
  uint32_t r = (x + 0x7fffu + ((x >> 16) & 1u)) >> 16;
  return (u16)r;
}
__device__ __forceinline__ float bf2f(u16 u) {
  return __uint_as_float(((uint32_t)u) << 16);
}
__device__ __forceinline__ float fast_sigmoid(float x) {
  return 1.0f / (1.0f + __expf(-x));
}
__device__ __forceinline__ float fast_tanh(float x) {
  return 1.0f - 2.0f / (__expf(2.0f * x) + 1.0f);
}

// ---------------------------------------------------------------------------
// fp32 -> bf16 convert, 8 elems/thread (two float4 loads, one uint4 store).
// All sizes here are multiples of 8.
// ---------------------------------------------------------------------------
__global__ void cvt_bf16x8_kernel(const f32x4v* __restrict__ src,
                                  u32x4* __restrict__ dst, int n8) {
  int i = blockIdx.x * blockDim.x + threadIdx.x;
  int stride = gridDim.x * blockDim.x;
  for (; i < n8; i += stride) {
    f32x4v a = src[2 * i];
    f32x4v b = src[2 * i + 1];
    u32x4 o;
    o.x = (u32)f2bf(a.x) | ((u32)f2bf(a.y) << 16);
    o.y = (u32)f2bf(a.z) | ((u32)f2bf(a.w) << 16);
    o.z = (u32)f2bf(b.x) | ((u32)f2bf(b.y) << 16);
    o.w = (u32)f2bf(b.z) | ((u32)f2bf(b.w) << 16);
    dst[i] = o;
  }
}

// ---------------------------------------------------------------------------
// bf16 GEMM, C[M,N] = A[M,K] * B[N,K]^T. OutT = float or u16 (bf16).
// 128x128 tile, BK=32, 4 waves; each wave 64x64 via 2x2 tiles of MFMA
// v_mfma_f32_32x32x16_bf16 (8 MFMA/K-iter vs 16 for 16x16x32 — fewer issue
// slots, 64 vs 77.6 MFMA-pipe cycles per wave-iter; ubench +15%).
//
// LDS: [row][32 u16] with XOR-swizzled 16B chunks: phys_chunk =
// logical_chunk ^ ((row>>1)&3). Staging (global_load_lds dest = wave-uniform
// base + lane*16, m104) applies the swizzle by permuting per-lane global
// SOURCE chunks. Fragment reads: any aligned 8-lane group covers all 8
// four-bank slots -> 0 conflicts (verified R3: SQ_LDS_BANK_CONFLICT=0).
// ---------------------------------------------------------------------------
template <typename OutT>
__global__ __launch_bounds__(256) void gemm_bt(const u16* __restrict__ A,
                                               const u16* __restrict__ B,
                                               OutT* __restrict__ C,
                                               int M, int N, int K) {
  __shared__ u16 As[128 * 32];
  __shared__ u16 Bs[128 * 32];

  const int tid = threadIdx.x;
  const int wave = tid >> 6;
  const int lane = tid & 63;
  const int m0 = blockIdx.x * 128;
  const int n0 = blockIdx.y * 128;
  const int wm = (wave & 1) * 64;   // wave quadrant
  const int wn = (wave >> 1) * 64;

  f32x16 acc[2][2] = {};

  // Staging: wave covers 32 rows (2 insts x 16 rows). Lane l: row_local=l>>2,
  // physical chunk l&3 -> fetch logical chunk (l&3) ^ ((l>>3)&3).
  const int srow = wave * 32 + (lane >> 2);
  const int scol = ((lane & 3) ^ ((lane >> 3) & 3)) * 8;  // swizzled source chunk
  const u16* Ag0 = A + (size_t)(m0 + srow) * K + scol;
  const u16* Ag1 = A + (size_t)(m0 + srow + 16) * K + scol;
  const u16* Bg0 = B + (size_t)(n0 + srow) * K + scol;
  const u16* Bg1 = B + (size_t)(n0 + srow + 16) * K + scol;
  u16* Al0 = &As[(wave * 32) * 32];
  u16* Al1 = &As[(wave * 32 + 16) * 32];
  u16* Bl0 = &Bs[(wave * 32) * 32];
  u16* Bl1 = &Bs[(wave * 32 + 16) * 32];

  // 32x32x16 fragment coords: row = lane&31, logical 16B chunk =
  // ks*2 + (lane>>5); phys chunk = logical ^ ((lane>>1)&3) (row bits 1-2).
  const int fr = lane & 31;
  const int fc = lane >> 5;
  const int fx = (lane >> 1) & 3;

  for (int k0 = 0; k0 < K; k0 += 32) {
    __builtin_amdgcn_global_load_lds(
        (__attribute__((address_space(1))) void*)(u16*)(Ag0 + k0),
        (__attribute__((address_space(3))) void*)Al0, 16, 0, 0);
    __builtin_amdgcn_global_load_lds(
        (__attribute__((address_space(1))) void*)(u16*)(Ag1 + k0),
        (__attribute__((address_space(3))) void*)Al1, 16, 0, 0);
    __builtin_amdgcn_global_load_lds(
        (__attribute__((address_space(1))) void*)(u16*)(Bg0 + k0),
        (__attribute__((address_space(3))) void*)Bl0, 16, 0, 0);
    __builtin_amdgcn_global_load_lds(
        (__attribute__((address_space(1))) void*)(u16*)(Bg1 + k0),
        (__attribute__((address_space(3))) void*)Bl1, 16, 0, 0);
    __syncthreads();

    bf16x8 af[2][2], bfg[2][2];
#pragma unroll
    for (int ks = 0; ks < 2; ++ks) {
      const int pc = ((ks * 2 + fc) ^ fx) * 8;
#pragma unroll
      for (int mt = 0; mt < 2; ++mt)
        af[mt][ks] = *(const bf16x8*)&As[(wm + mt * 32 + fr) * 32 + pc];
#pragma unroll
      for (int nt = 0; nt < 2; ++nt)
        bfg[nt][ks] = *(const bf16x8*)&Bs[(wn + nt * 32 + fr) * 32 + pc];
    }

#pragma unroll
    for (int ks = 0; ks < 2; ++ks)
#pragma unroll
      for (int mt = 0; mt < 2; ++mt)
#pragma unroll
        for (int nt = 0; nt < 2; ++nt)
          acc[mt][nt] = __builtin_amdgcn_mfma_f32_32x32x16_bf16(
              af[mt][ks], bfg[nt][ks], acc[mt][nt], 0, 0, 0);

    __syncthreads();
  }

  // Epilogue: 32x32 C/D layout col=lane&31, row=(reg&3)+8*(reg>>2)+4*(lane>>5)
  // (m74/m101-verified).
  const int ccol = lane & 31;
  const int rbase = 4 * (lane >> 5);
#pragma unroll
  for (int mt = 0; mt < 2; ++mt) {
#pragma unroll
    for (int nt = 0; nt < 2; ++nt) {
      const size_t cb = (size_t)(n0 + wn + nt * 32 + ccol);
      const size_t rb = (size_t)(m0 + wm + mt * 32 + rbase);
#pragma unroll
      for (int reg = 0; reg < 16; ++reg) {
        const int r = (reg & 3) + 8 * (reg >> 2);
        OutT* Cp = C + (rb + r) * N + cb;
        if constexpr (sizeof(OutT) == 2)
          *Cp = (OutT)f2bf(acc[mt][nt][reg]);
        else
          *Cp = acc[mt][nt][reg];
      }
    }
  }
}

// ---------------------------------------------------------------------------
// Scan phase A: per-chunk local pass (state_in = 0):
//   prefix = cumprod(a); acc = cumsum(u / max(prefix,1e-6))
// One wave per (b, chunk, h); lane owns d=lane and d=lane+64.
// Emits chunk carries P = prefix[63], L = prefix[63]*acc[63].
// ---------------------------------------------------------------------------
__global__ __launch_bounds__(64) void scan_chunk(const u16* __restrict__ proj,
                                                 float* __restrict__ Pc,
                                                 float* __restrict__ Lc) {
  const int idx = blockIdx.x;            // ((b*NC + c)*HH + h)
  const int h = idx & (HH - 1);
  const int c = (idx >> 4) & (NC - 1);
  const int b = idx >> 10;
  const int lane = threadIdx.x;

  const size_t row0 = (size_t)(b * SS + c * CC) * D5 + h * HD;

  float p0 = 1.0f, a0 = 0.0f, p1 = 1.0f, a1 = 0.0f;
  for (int t = 0; t < CC; ++t) {
    const size_t rp = row0 + (size_t)t * D5;
    float k0 = bf2f(proj[rp + DD + lane]);
    float k1 = bf2f(proj[rp + DD + lane + 64]);
    float v0 = bf2f(proj[rp + 2 * DD + lane]);
    float v1 = bf2f(proj[rp + 2 * DD + lane + 64]);
    float ar0 = bf2f(proj[rp + 3 * DD + lane]);
    float ar1 = bf2f(proj[rp + 3 * DD + lane + 64]);
    float aa0 = fminf(fmaxf(fast_sigmoid(ar0 + 2.0f), 0.6f), 0.9995f);
    float aa1 = fminf(fmaxf(fast_sigmoid(ar1 + 2.0f), 0.6f), 0.9995f);
    p0 *= aa0;
    p1 *= aa1;
    a0 += fast_tanh(k0) * v0 / fmaxf(p0, 1e-6f);
    a1 += fast_tanh(k1) * v1 / fmaxf(p1, 1e-6f);
  }
  const size_t ci = ((size_t)(b * NC + c) * HH + h) * HD;  // [b][c][h*hd]
  Pc[ci + lane] = p0;
  Pc[ci + lane + 64] = p1;
  Lc[ci + lane] = p0 * a0;
  Lc[ci + lane + 64] = p1 * a1;
}

// ---------------------------------------------------------------------------
// Scan phase B: inter-chunk carry. One thread per (b, h*hd) channel.
// ---------------------------------------------------------------------------
__global__ void scan_carry(const float* __restrict__ Pc, const float* __restrict__ Lc,
                           float* __restrict__ Sin) {
  const int t = blockIdx.x * blockDim.x + threadIdx.x;  // < BB*DD
  const int b = t >> 11;
  const int hd = t & (DD - 1);
  float state = 0.0f;
  for (int c = 0; c < NC; ++c) {
    const size_t i = (size_t)(b * NC + c) * DD + hd;
    Sin[i] = state;
    state = Pc[i] * state + Lc[i];
  }
}

// ---------------------------------------------------------------------------
// Scan phase C / finalize: recompute chunk-local recurrence, combine with
// carried state: mem_t = prefix_t*(state_in + acc_t); RMS-norm q; gates; y.
// One wave per (b, chunk, h); RMS reduction = pure wave shfl_xor.
// ---------------------------------------------------------------------------
__global__ __launch_bounds__(64) void finalize_y(const u16* __restrict__ proj,
                                                 const float* __restrict__ Sin,
                                                 u16* __restrict__ y) {
  const int idx = blockIdx.x;            // ((b*NC + c)*HH + h)
  const int h = idx & (HH - 1);
  const int c = (idx >> 4) & (NC - 1);
  const int b = idx >> 10;
  const int lane = threadIdx.x;

  const size_t row0 = (size_t)(b * SS + c * CC) * D5 + h * HD;
  const size_t out0 = (size_t)(b * SS + c * CC) * DD + h * HD;
  const size_t sinb = (size_t)(b * NC + c) * DD + h * HD;
  const float sin0 = Sin[sinb + lane];
  const float sin1 = Sin[sinb + lane + 64];

  float p0 = 1.0f, a0 = 0.0f, p1 = 1.0f, a1 = 0.0f;
  for (int t = 0; t < CC; ++t) {
    const size_t rp = row0 + (size_t)t * D5;
    const float q0 = bf2f(proj[rp + lane]);
    const float q1 = bf2f(proj[rp + lane + 64]);
    const float k0 = bf2f(proj[rp + DD + lane]);
    const float k1 = bf2f(proj[rp + DD + lane + 64]);
    const float v0 = bf2f(proj[rp + 2 * DD + lane]);
    const float v1 = bf2f(proj[rp + 2 * DD + lane + 64]);
    const float ar0 = bf2f(proj[rp + 3 * DD + lane]);
    const float ar1 = bf2f(proj[rp + 3 * DD + lane + 64]);
    const float g0 = bf2f(proj[rp + 4 * DD + lane]);
    const float g1 = bf2f(proj[rp + 4 * DD + lane + 64]);

    const float aa0 = fminf(fmaxf(fast_sigmoid(ar0 + 2.0f), 0.6f), 0.9995f);
    const float aa1 = fminf(fmaxf(fast_sigmoid(ar1 + 2.0f), 0.6f), 0.9995f);
    p0 *= aa0;
    p1 *= aa1;
    a0 += fast_tanh(k0) * v0 / fmaxf(p0, 1e-6f);
    a1 += fast_tanh(k1) * v1 / fmaxf(p1, 1e-6f);
    const float mem0 = p0 * (sin0 + a0);
    const float mem1 = p1 * (sin1 + a1);

    float ss = q0 * q0 + q1 * q1;
#pragma unroll
    for (int m = 32; m; m >>= 1) ss += __shfl_xor(ss, m);
    const float rn = rsqrtf(ss * (1.0f / 128.0f) + RMS_EPS);

    const float gt0 = fast_sigmoid(g0);
    const float gt1 = fast_sigmoid(g1);
    y[out0 + (size_t)t * DD + lane] = f2bf(gt0 * (q0 * rn * mem0) + (1.0f - gt0) * v0);
    y[out0 + (size_t)t * DD + lane + 64] = f2bf(gt1 * (q1 * rn * mem1) + (1.0f - gt1) * v1);
  }
}

// ---------------------------------------------------------------------------
extern "C" void kernel_launch(void* const* d_in, const int* in_sizes, int n_in,
                              void* d_out, int out_size, void* d_ws, size_t ws_size,
                              hipStream_t stream) {
  const float* x = (const float*)d_in[0];      // [2,4096,2048]
  const float* w_in = (const float*)d_in[1];   // [10240,2048]
  const float* w_out = (const float*)d_in[2];  // [2048,2048]
  float* out = (float*)d_out;                  // [2,4096,2048] fp32

  char* ws = (char*)d_ws;
  size_t off = 0;
  auto alloc = [&](size_t bytes) -> void* {
    void* p = ws + off;
    off += (bytes + 255) & ~(size_t)255;
    return p;
  };
  const size_t nBS = (size_t)BB * SS;              // 8192
  u16* projb = (u16*)alloc(nBS * D5 * 2);          // 167.8 MB (bf16 proj)
  u16* xb    = (u16*)alloc(nBS * DD * 2);          // 33.6 MB (reused as yb)
  u16* wib   = (u16*)alloc((size_t)D5 * DD * 2);   // 41.9 MB
  u16* wob   = (u16*)alloc((size_t)DD * DD * 2);   // 8.4 MB
  float* Pc  = (float*)alloc((size_t)BB * NC * DD * 4);  // 1 MB
  float* Lc  = (float*)alloc((size_t)BB * NC * DD * 4);  // 1 MB
  float* Sin = (float*)alloc((size_t)BB * NC * DD * 4);  // 1 MB
  u16* yb = xb;  // xb dead after GEMM1; reuse for y
  (void)in_sizes; (void)n_in; (void)out_size;

  // Workspace guard: clean zero-output failure instead of memory fault.
  if (off > ws_size) return;

  // 1) bf16 casts (vectorized: 8 elems/thread)
  cvt_bf16x8_kernel<<<1024, 256, 0, stream>>>((const f32x4v*)x, (u32x4*)xb,
                                              (int)(nBS * DD / 8));
  cvt_bf16x8_kernel<<<1024, 256, 0, stream>>>((const f32x4v*)w_in, (u32x4*)wib,
                                              (int)((size_t)D5 * DD / 8));
  cvt_bf16x8_kernel<<<1024, 256, 0, stream>>>((const f32x4v*)w_out, (u32x4*)wob,
                                              (int)((size_t)DD * DD / 8));

  // 2) proj = x @ w_in^T   [8192 x 10240], K=2048, bf16 out
  gemm_bt<u16><<<dim3(64, 80), 256, 0, stream>>>(xb, wib, projb, 8192, 10240, 2048);

  // 3) chunk-local scan -> per-chunk carries only
  scan_chunk<<<BB * NC * HH, 64, 0, stream>>>(projb, Pc, Lc);

  // 4) inter-chunk carry scan
  scan_carry<<<16, 256, 0, stream>>>(Pc, Lc, Sin);

  // 5) finalize y (recompute local scan, rmsnorm q, gates) -> bf16 (into xb)
  finalize_y<<<BB * NC * HH, 64, 0, stream>>>(projb, Sin, yb);

  // 6) out = y @ w_out^T   [8192 x 2048], K=2048, fp32 out
  gemm_bt<float><<<dim3(64, 16), 256, 0, stream>>>(yb, wob, out, 8192, 2048, 2048);
}